// Round 8
// baseline (318.907 us; speedup 1.0000x reference)
//
#include <hip/hip_runtime.h>
#include <math.h>

#define N_ROWS  65536
#define EDIM    256
#define NE      1024
#define BETA    0.25f
#define LAMBDA  0.99f

// margin: worst-case two-sided bf16-filter error bound is 4.8e-3
// (2 * 2^-7 * ||z||*||e|| per side, Cauchy-Schwarz); 8e-3 = verified-passing.
#define MARGIN  8e-3f
#define QCAP    2048

// ---------------- ws layout (float units) ----------------
// [0]        loss accumulator
// [64]       e_sq[1024]       (numpy-exact fp32 row sums of emb*emb)
// [67584]    b_frag           (bf16 emb in MFMA fragment order, 512 KB)
// [198656]   sorted[65536]    (int; row ids grouped by code)
// [264192]   idx[65536] (int)
// [329728]   counts[1024]     (float, for final_kernel)
// [330752]   cnt_i[1024]      (int histogram)
// [331776]   offs_i[1024]     (int exclusive prefix)
// [332800]   cursor_i[1024]   (int scatter cursors)

// out layout (float units): loss, z_q_st, idx, perplexity, N_t, m_t
#define O_ZQ   1
#define O_IDX  16777217
#define O_PERP 16842753
#define O_NT   16842754
#define O_MT   16843778

typedef __attribute__((ext_vector_type(8))) short short8;
typedef __attribute__((ext_vector_type(4))) float f32x4;

// RNE float -> bf16 (no NaN in this data)
__device__ __forceinline__ unsigned short f2bf(float f) {
    unsigned u = __float_as_uint(f);
    return (unsigned short)((u + 0x7fffu + ((u >> 16) & 1u)) >> 16);
}

// ---------------------------------------------------------------------------
// prep_b: emb -> bf16 in MFMA fragment order; zero loss + histogram. (R6-proven)
// Fragment entry (16B = short8) index: (ctg*8 + ks)*64 + lane, holding
// [k = ks*32 + lg*8 .. +7][col = ctg*16 + l15]  (lane = lg*16 + l15).
__global__ __launch_bounds__(64) void prep_b_kernel(const float* __restrict__ emb,
                                                    unsigned* __restrict__ bfrag_u32,
                                                    float* __restrict__ loss_acc,
                                                    int* __restrict__ cnt) {
    int j = blockIdx.x;          // code id (column)
    int l = threadIdx.x;         // 0..63
    float4 v = ((const float4*)(emb + (size_t)j * EDIM))[l];
    unsigned lo = (unsigned)f2bf(v.x) | ((unsigned)f2bf(v.y) << 16);
    unsigned hi = (unsigned)f2bf(v.z) | ((unsigned)f2bf(v.w) << 16);
    int base = ((((j >> 4) * 8 + (l >> 3)) * 64) + ((l >> 1) & 3) * 16 + (j & 15)) * 4
             + 2 * (l & 1);
    bfrag_u32[base]     = lo;
    bfrag_u32[base + 1] = hi;
    if (l == 0) cnt[j] = 0;
    if (j == 0 && l == 0) *loss_acc = 0.0f;
}

// ---------------------------------------------------------------------------
// sq_kernel (emb): numpy-pairwise-exact fp32 sum of squares — UNCHANGED (R6)
__global__ __launch_bounds__(256) void sq_kernel(const float* __restrict__ src,
                                                 float* __restrict__ dst) {
    const int tid = threadIdx.x;
    const int grp = tid >> 4;          // 16 rows per block
    const int q   = tid & 15;
    const int row = blockIdx.x * 16 + grp;
    const int h = q >> 3, j = q & 7;
    const float* __restrict__ p = src + (size_t)row * EDIM + h * 128 + j;
    float acc = __fmul_rn(p[0], p[0]);
    #pragma unroll
    for (int t = 1; t < 16; ++t) {
        float v = p[8 * t];
        acc = __fadd_rn(acc, __fmul_rn(v, v));
    }
    acc = __fadd_rn(acc, __shfl_xor(acc, 1));
    acc = __fadd_rn(acc, __shfl_xor(acc, 2));
    acc = __fadd_rn(acc, __shfl_xor(acc, 4));
    acc = __fadd_rn(acc, __shfl_xor(acc, 8));
    if (q == 0) dst[row] = acc;
}

// ---------------------------------------------------------------------------
// argmin_kernel v8: column-split, barrier-free main loop, SWAPPED MFMA operands.
//  - 32 rows/block, 256 thr (4 waves), grid 2048, 12 waves/CU.
//  - Wave w owns cols [256w, 256w+256); B read direct from L2 (fragment order).
//  - mfma(b, a): C[emb_col][z_row] -> z_row = lane&15, emb_col = lg*4+reg.
//    Row-min = 3 VALU fmin + 2 shfl_xor(16,32). rm is 2 regs.
//  - Per-wave rm is a valid upper bound (winner always enqueued: t(c*) <=
//    rm_w + 2*bound <= rm_w + MARGIN); post-filter uses exact rmF = min over
//    waves; refine compares exact fp32 d -> idx/loss bit-identical to R6.
__global__ __launch_bounds__(256, 3) void argmin_kernel(const float* __restrict__ z,
                                                        const float* __restrict__ emb,
                                                        const short8* __restrict__ bfrag,
                                                        const float* __restrict__ e_sq,
                                                        int* __restrict__ idx_out,
                                                        float* __restrict__ out_zq,
                                                        float* __restrict__ out_idx,
                                                        float* __restrict__ loss_acc,
                                                        int* __restrict__ cnt) {
    __shared__ float e_lds[NE];                      // 4 KB
    __shared__ uint2 queue[QCAP];                    // 16 KB (rl|col, t-bits)
    __shared__ unsigned long long best_s[32];        // 256 B
    __shared__ float rmW_s[4][32];                   // 512 B
    __shared__ float rmF_s[32];
    __shared__ float zsq_s[32];
    __shared__ int   idx_s[32];
    __shared__ int   qcnt;

    const int tid = threadIdx.x;
    const int wid = tid >> 6, lane = tid & 63;
    const int l15 = lane & 15, lg = lane >> 4;
    const int row0 = blockIdx.x * 32;

    if (tid < 32) best_s[tid] = ~0ull;
    if (tid == 0) qcnt = 0;
    #pragma unroll
    for (int i = 0; i < 4; ++i) e_lds[tid + 256 * i] = e_sq[tid + 256 * i];

    // ---- A fragments: each wave loads all 32 rows (L2 serves the re-read);
    //      zsq on the fly (additive per-row constant; cancels in argmin) ----
    short8 a[2][8];
    #pragma unroll
    for (int rt = 0; rt < 2; ++rt) {
        float zs = 0.f;
        #pragma unroll
        for (int ks = 0; ks < 8; ++ks) {
            const float* zp = z + (size_t)(row0 + rt * 16 + l15) * EDIM + ks * 32 + lg * 8;
            float4 f0 = *(const float4*)zp;
            float4 f1 = *(const float4*)(zp + 4);
            zs += f0.x * f0.x + f0.y * f0.y + f0.z * f0.z + f0.w * f0.w
                + f1.x * f1.x + f1.y * f1.y + f1.z * f1.z + f1.w * f1.w;
            union { short8 s; unsigned short u[8]; } pk;
            pk.u[0] = f2bf(f0.x); pk.u[1] = f2bf(f0.y); pk.u[2] = f2bf(f0.z); pk.u[3] = f2bf(f0.w);
            pk.u[4] = f2bf(f1.x); pk.u[5] = f2bf(f1.y); pk.u[6] = f2bf(f1.z); pk.u[7] = f2bf(f1.w);
            a[rt][ks] = pk.s;
        }
        zs += __shfl_xor(zs, 16);        // combine lg quarters -> full row sum
        zs += __shfl_xor(zs, 32);
        if (wid == rt && lg == 0) zsq_s[rt * 16 + l15] = zs;
    }

    float rm[2] = {1e30f, 1e30f};
    __syncthreads();   // e_lds + zsq + init visible; main loop is barrier-free

    // ---- main loop: 16 chunks of 16 cols from this wave's range; B from L2 ----
    for (int ch = 0; ch < 16; ++ch) {
        const int cb = wid * 256 + ch * 16;
        short8 b[8];
        #pragma unroll
        for (int ks = 0; ks < 8; ++ks)
            b[ks] = bfrag[((size_t)(wid * 16 + ch) * 8 + ks) * 64 + lane]; // coalesced 1KB/wave

        f32x4 acc[2];
        #pragma unroll
        for (int rt = 0; rt < 2; ++rt) acc[rt] = (f32x4){0.f, 0.f, 0.f, 0.f};
        #pragma unroll
        for (int ks = 0; ks < 8; ++ks)
            #pragma unroll
            for (int rt = 0; rt < 2; ++rt)   // swapped operands: C[emb_col][z_row]
                acc[rt] = __builtin_amdgcn_mfma_f32_16x16x32_bf16(b[ks], a[rt][ks], acc[rt], 0, 0, 0);

        const float4 eq = ((const float4*)e_lds)[(cb >> 2) + lg];  // cols cb+lg*4 ..+3

        #pragma unroll
        for (int rt = 0; rt < 2; ++rt) {
            float t0 = __fsub_rn(eq.x, __fmul_rn(2.0f, acc[rt][0]));
            float t1 = __fsub_rn(eq.y, __fmul_rn(2.0f, acc[rt][1]));
            float t2 = __fsub_rn(eq.z, __fmul_rn(2.0f, acc[rt][2]));
            float t3 = __fsub_rn(eq.w, __fmul_rn(2.0f, acc[rt][3]));
            float m = fminf(fminf(t0, t1), fminf(t2, t3));
            m = fminf(m, __shfl_xor(m, 16));   // combine the 4 lg col-groups
            m = fminf(m, __shfl_xor(m, 32));   // -> row-chunk min for row l15
            rm[rt] = fminf(rm[rt], m);
            const float thr = rm[rt] + MARGIN;
            const int rl = rt * 16 + l15;
            if (t0 <= thr) { int s = atomicAdd(&qcnt, 1); if (s < QCAP) queue[s] = make_uint2((rl << 10) | (cb + lg * 4 + 0), __float_as_uint(t0)); }
            if (t1 <= thr) { int s = atomicAdd(&qcnt, 1); if (s < QCAP) queue[s] = make_uint2((rl << 10) | (cb + lg * 4 + 1), __float_as_uint(t1)); }
            if (t2 <= thr) { int s = atomicAdd(&qcnt, 1); if (s < QCAP) queue[s] = make_uint2((rl << 10) | (cb + lg * 4 + 2), __float_as_uint(t2)); }
            if (t3 <= thr) { int s = atomicAdd(&qcnt, 1); if (s < QCAP) queue[s] = make_uint2((rl << 10) | (cb + lg * 4 + 3), __float_as_uint(t3)); }
        }
    }

    // ---- publish per-wave final mins; rmF = exact row min over 4 waves ----
    if (lg == 0) {
        rmW_s[wid][l15]      = rm[0];
        rmW_s[wid][16 + l15] = rm[1];
    }
    __syncthreads();
    if (tid < 32)
        rmF_s[tid] = fminf(fminf(rmW_s[0][tid], rmW_s[1][tid]),
                           fminf(rmW_s[2][tid], rmW_s[3][tid]));
    __syncthreads();

    // ---- cooperative exact refine: 8 lanes per candidate, post-filtered ----
    {
        int nq = qcnt; if (nq > QCAP) nq = QCAP;
        const int g = tid >> 3, q = tid & 7;      // 32 groups
        for (int e = g; e < nq; e += 32) {
            uint2 ent = queue[e];
            int rl = ent.x >> 10, col = ent.x & 1023;
            if (__uint_as_float(ent.y) > rmF_s[rl] + MARGIN) continue;  // cull
            const float4* zr = (const float4*)(z + (size_t)(row0 + rl) * EDIM);
            const float4* er = (const float4*)(emb + (size_t)col * EDIM);
            float ae = 0.f;
            #pragma unroll
            for (int i = 0; i < 8; ++i) {
                float4 x = zr[q + 8 * i], y = er[q + 8 * i];
                ae = __fmaf_rn(x.x, y.x, ae);
                ae = __fmaf_rn(x.y, y.y, ae);
                ae = __fmaf_rn(x.z, y.z, ae);
                ae = __fmaf_rn(x.w, y.w, ae);
            }
            ae = __fadd_rn(ae, __shfl_xor(ae, 1));
            ae = __fadd_rn(ae, __shfl_xor(ae, 2));
            ae = __fadd_rn(ae, __shfl_xor(ae, 4));
            if (q == 0) {
                float d = __fsub_rn(__fadd_rn(zsq_s[rl], e_lds[col]), __fmul_rn(2.0f, ae));
                unsigned u = __float_as_uint(d);
                u = (u & 0x80000000u) ? ~u : (u | 0x80000000u);   // order-preserving map
                unsigned long long key = ((unsigned long long)u << 32) | (unsigned)col;
                atomicMin(&best_s[rl], key);
            }
        }
    }

    __syncthreads();
    if (tid < 32) {
        unsigned long long k = best_s[tid];
        int id = (int)(k & 1023u);       // valid keys carry col in low bits;
                                         // clamp guards any unset row (no wild gather)
        idx_out[row0 + tid] = id;
        out_idx[row0 + tid] = (float)id;
        idx_s[tid] = id;
        atomicAdd(&cnt[id], 1);          // fused histogram
    }
    __syncthreads();

    // ---- z_q gather + store: one row per wave per iter (1KB contiguous) ----
    const float4* e4 = (const float4*)emb;
    #pragma unroll
    for (int i = 0; i < 8; ++i) {
        int flat = tid + i * 256;
        int r = flat >> 6, c4 = flat & 63;
        int id = idx_s[r];
        float4 e = e4[(size_t)id * 64 + c4];
        float* o = out_zq + (size_t)(row0 + r) * EDIM + c4 * 4;  // base odd-float: scalar stores
        o[0] = e.x; o[1] = e.y; o[2] = e.z; o[3] = e.w;
    }

    // ---- loss: decode the winning refined d per row (wave 0), accumulate ----
    if (wid == 0) {
        float lp = 0.f;
        if (lane < 32) {
            unsigned m = (unsigned)(best_s[lane] >> 32);
            unsigned bits = (m & 0x80000000u) ? (m & 0x7fffffffu) : ~m;
            lp = __uint_as_float(bits);
        }
        #pragma unroll
        for (int mm = 32; mm; mm >>= 1) lp += __shfl_down(lp, mm);
        if (lane == 0) atomicAdd(loss_acc, lp);
    }
}

// ---------------------------------------------------------------------------
// stats via counting sort: scan (offsets, N_t, counts) -> scatter -> msum
__global__ __launch_bounds__(1024) void scan_kernel(const int* __restrict__ cnt,
                                                    const float* __restrict__ N_t,
                                                    float* __restrict__ outN,
                                                    float* __restrict__ counts_f,
                                                    int* __restrict__ offs,
                                                    int* __restrict__ cursor) {
    __shared__ int s[1024];
    const int tid = threadIdx.x;
    int c = cnt[tid];
    s[tid] = c;
    __syncthreads();
    for (int d = 1; d < 1024; d <<= 1) {
        int v = (tid >= d) ? s[tid - d] : 0;
        __syncthreads();
        s[tid] += v;
        __syncthreads();
    }
    int excl = s[tid] - c;
    offs[tid] = excl;
    cursor[tid] = excl;
    counts_f[tid] = (float)c;
    float Nold = N_t[tid];
    outN[tid] = (c > 0) ? Nold * LAMBDA + (float)c * (1.0f - LAMBDA) : Nold;
}

__global__ __launch_bounds__(256) void scatter_kernel(const int* __restrict__ idx,
                                                      int* __restrict__ cursor,
                                                      int* __restrict__ sorted) {
    int i = blockIdx.x * 256 + threadIdx.x;
    int p = atomicAdd(&cursor[idx[i]], 1);
    sorted[p] = i;
}

__global__ __launch_bounds__(512) void msum_kernel(const float* __restrict__ z,
                                                   const int* __restrict__ sorted,
                                                   const int* __restrict__ offs,
                                                   const int* __restrict__ cnt,
                                                   const float* __restrict__ m_t,
                                                   float* __restrict__ outM) {
    const int j = blockIdx.x;
    const int tid = threadIdx.x, w = tid >> 6, lane = tid & 63;
    const int n = cnt[j], start = offs[j];
    float4 acc = make_float4(0.f, 0.f, 0.f, 0.f);
    for (int e = w; e < n; e += 8) {
        float4 v = ((const float4*)(z + (size_t)sorted[start + e] * EDIM))[lane];
        acc.x += v.x; acc.y += v.y; acc.z += v.z; acc.w += v.w;
    }
    __shared__ float red[8 * 256];
    *(float4*)(red + w * 256 + lane * 4) = acc;
    __syncthreads();
    if (tid < 256) {
        float s = 0.f;
        #pragma unroll
        for (int ww = 0; ww < 8; ++ww) s += red[ww * 256 + tid];
        float mold = m_t[(size_t)j * EDIM + tid];
        outM[(size_t)j * EDIM + tid] = (n > 0) ? mold * LAMBDA + s * (1.0f - LAMBDA) : mold;
    }
}

// ---------------------------------------------------------------------------
// finalize — UNCHANGED
__global__ __launch_bounds__(256) void final_kernel(const float* __restrict__ counts,
                                                    const float* __restrict__ loss_acc,
                                                    float* __restrict__ out_loss,
                                                    float* __restrict__ out_perp) {
    const int tid = threadIdx.x, w = tid >> 6, lane = tid & 63;
    float h = 0.f;
    for (int c = tid; c < NE; c += 256) {
        float em = counts[c] * (1.0f / (float)N_ROWS);
        h += em * logf(em + 1e-10f);
    }
    #pragma unroll
    for (int m = 32; m; m >>= 1) h += __shfl_down(h, m);
    __shared__ float red[4];
    if (lane == 0) red[w] = h;
    __syncthreads();
    if (tid == 0) {
        float H = red[0] + red[1] + red[2] + red[3];
        out_perp[0] = expf(-H);
        out_loss[0] = BETA * loss_acc[0] * (1.0f / (float)(N_ROWS * EDIM));
    }
}

// ---------------------------------------------------------------------------
extern "C" void kernel_launch(void* const* d_in, const int* in_sizes, int n_in,
                              void* d_out, int out_size, void* d_ws, size_t ws_size,
                              hipStream_t stream) {
    const float* z   = (const float*)d_in[0];
    const float* emb = (const float*)d_in[1];
    const float* N_t = (const float*)d_in[2];
    const float* m_t = (const float*)d_in[3];
    float* out = (float*)d_out;
    float* ws  = (float*)d_ws;

    float* loss_acc   = ws;
    float* e_sq       = ws + 64;
    unsigned* bfrag_u = (unsigned*)(ws + 67584);
    int*   sorted     = (int*)(ws + 198656);
    int*   idx1       = (int*)(ws + 264192);
    float* counts     = ws + 329728;
    int*   cnt_i      = (int*)(ws + 330752);
    int*   offs_i     = (int*)(ws + 331776);
    int*   cursor_i   = (int*)(ws + 332800);

    prep_b_kernel<<<NE, 64, 0, stream>>>(emb, bfrag_u, loss_acc, cnt_i);
    sq_kernel<<<NE / 16, 256, 0, stream>>>(emb, e_sq);
    argmin_kernel<<<N_ROWS / 32, 256, 0, stream>>>(z, emb, (const short8*)bfrag_u,
                                                   e_sq, idx1,
                                                   out + O_ZQ, out + O_IDX, loss_acc, cnt_i);
    scan_kernel<<<1, 1024, 0, stream>>>(cnt_i, N_t, out + O_NT, counts, offs_i, cursor_i);
    scatter_kernel<<<N_ROWS / 256, 256, 0, stream>>>(idx1, cursor_i, sorted);
    msum_kernel<<<NE, 512, 0, stream>>>(z, sorted, offs_i, cnt_i, m_t, out + O_MT);
    final_kernel<<<1, 256, 0, stream>>>(counts, loss_acc, out, out + O_PERP);
}

// Round 9
// 300.405 us; speedup vs baseline: 1.0616x; 1.0616x over previous
//
#include <hip/hip_runtime.h>
#include <math.h>

#define N_ROWS  65536
#define EDIM    256
#define NE      1024
#define BETA    0.25f
#define LAMBDA  0.99f

// margin: worst-case two-sided bf16-filter error bound is 4.8e-3
// (2 * 2^-7 * ||z||*||e|| per side, Cauchy-Schwarz); 8e-3 = verified-passing.
#define MARGIN  8e-3f
#define QCAP    2048

// ---------------- ws layout (float units) ----------------
// [0]        loss accumulator
// [64]       e_sq[1024]       (numpy-exact fp32 row sums of emb*emb)
// [67584]    b_frag           (bf16 emb in MFMA fragment order, 512 KB)
// [198656]   sorted[65536]    (int; row ids grouped by code)
// [264192]   idx[65536] (int)
// [329728]   counts[1024]     (float, for final_kernel)
// [330752]   cnt_i[1024]      (int histogram)
// [331776]   offs_i[1024]     (int exclusive prefix)
// [332800]   cursor_i[1024]   (int scatter cursors)

// out layout (float units): loss, z_q_st, idx, perplexity, N_t, m_t
#define O_ZQ   1
#define O_IDX  16777217
#define O_PERP 16842753
#define O_NT   16842754
#define O_MT   16843778

typedef __attribute__((ext_vector_type(8))) short short8;
typedef __attribute__((ext_vector_type(4))) float f32x4;

// RNE float -> bf16 (no NaN in this data)
__device__ __forceinline__ unsigned short f2bf(float f) {
    unsigned u = __float_as_uint(f);
    return (unsigned short)((u + 0x7fffu + ((u >> 16) & 1u)) >> 16);
}

// ---------------------------------------------------------------------------
// prep_b: emb -> bf16 in MFMA fragment order; zero loss + histogram. (R6-proven)
// Fragment entry (16B = short8) index: (ctg*8 + ks)*64 + lane, holding
// [k = ks*32 + lg*8 .. +7][col = ctg*16 + l15]  (lane = lg*16 + l15).
__global__ __launch_bounds__(64) void prep_b_kernel(const float* __restrict__ emb,
                                                    unsigned* __restrict__ bfrag_u32,
                                                    float* __restrict__ loss_acc,
                                                    int* __restrict__ cnt) {
    int j = blockIdx.x;          // code id (column)
    int l = threadIdx.x;         // 0..63
    float4 v = ((const float4*)(emb + (size_t)j * EDIM))[l];
    unsigned lo = (unsigned)f2bf(v.x) | ((unsigned)f2bf(v.y) << 16);
    unsigned hi = (unsigned)f2bf(v.z) | ((unsigned)f2bf(v.w) << 16);
    int base = ((((j >> 4) * 8 + (l >> 3)) * 64) + ((l >> 1) & 3) * 16 + (j & 15)) * 4
             + 2 * (l & 1);
    bfrag_u32[base]     = lo;
    bfrag_u32[base + 1] = hi;
    if (l == 0) cnt[j] = 0;
    if (j == 0 && l == 0) *loss_acc = 0.0f;
}

// ---------------------------------------------------------------------------
// sq_kernel (emb): numpy-pairwise-exact fp32 sum of squares — UNCHANGED (R6)
__global__ __launch_bounds__(256) void sq_kernel(const float* __restrict__ src,
                                                 float* __restrict__ dst) {
    const int tid = threadIdx.x;
    const int grp = tid >> 4;          // 16 rows per block
    const int q   = tid & 15;
    const int row = blockIdx.x * 16 + grp;
    const int h = q >> 3, j = q & 7;
    const float* __restrict__ p = src + (size_t)row * EDIM + h * 128 + j;
    float acc = __fmul_rn(p[0], p[0]);
    #pragma unroll
    for (int t = 1; t < 16; ++t) {
        float v = p[8 * t];
        acc = __fadd_rn(acc, __fmul_rn(v, v));
    }
    acc = __fadd_rn(acc, __shfl_xor(acc, 1));
    acc = __fadd_rn(acc, __shfl_xor(acc, 2));
    acc = __fadd_rn(acc, __shfl_xor(acc, 4));
    acc = __fadd_rn(acc, __shfl_xor(acc, 8));
    if (q == 0) dst[row] = acc;
}

// ---------------------------------------------------------------------------
// argmin_kernel v9: R8 structure (column-split, barrier-free, swapped MFMA)
// + (1) cooperative LDS A-stage: the 16 (rt,ks) fragment pairs are converted
//   once (4 pairs/wave) instead of 4x redundantly -> A-phase VALU / 4;
// + (2) register double-buffered B prefetch (bA/bB): next chunk's 8 loads in
//   flight under current chunk's MFMA+filter -> L2 latency hidden;
// + (3) filter t via single fmaf(-2,acc,eq).
// Filter/queue/post-filter/refine/loss machinery unchanged from R8.
__global__ __launch_bounds__(256, 3) void argmin_kernel(const float* __restrict__ z,
                                                        const float* __restrict__ emb,
                                                        const short8* __restrict__ bfrag,
                                                        const float* __restrict__ e_sq,
                                                        int* __restrict__ idx_out,
                                                        float* __restrict__ out_zq,
                                                        float* __restrict__ out_idx,
                                                        float* __restrict__ loss_acc,
                                                        int* __restrict__ cnt) {
    __shared__ __align__(16) uint4 A_stg[16 * 64];   // 16 KB fragment staging
    __shared__ float e_lds[NE];                      // 4 KB
    __shared__ uint2 queue[QCAP];                    // 16 KB (rl|col, t-bits)
    __shared__ unsigned long long best_s[32];        // 256 B
    __shared__ float rmW_s[4][32];                   // 512 B
    __shared__ float rmF_s[32];
    __shared__ float zsqP[4][16];
    __shared__ float zsq_s[32];
    __shared__ int   idx_s[32];
    __shared__ int   qcnt;

    const int tid = threadIdx.x;
    const int wid = tid >> 6, lane = tid & 63;
    const int l15 = lane & 15, lg = lane >> 4;
    const int row0 = blockIdx.x * 32;

    if (tid < 32) best_s[tid] = ~0ull;
    if (tid == 0) qcnt = 0;
    #pragma unroll
    for (int i = 0; i < 4; ++i) e_lds[tid + 256 * i] = e_sq[tid + 256 * i];

    // ---- cooperative A-stage: wave w converts pairs p = 4w..4w+3 (p=rt*8+ks);
    //      each (row,k) converted exactly once; zsq ks-half partials on the fly ----
    {
        float zs = 0.f;
        #pragma unroll
        for (int i = 0; i < 4; ++i) {
            const int p  = wid * 4 + i;
            const int rt = p >> 3, ks = p & 7;
            const float* zp = z + (size_t)(row0 + rt * 16 + l15) * EDIM + ks * 32 + lg * 8;
            float4 f0 = *(const float4*)zp;
            float4 f1 = *(const float4*)(zp + 4);
            zs += f0.x * f0.x + f0.y * f0.y + f0.z * f0.z + f0.w * f0.w
                + f1.x * f1.x + f1.y * f1.y + f1.z * f1.z + f1.w * f1.w;
            union { short8 s; unsigned short u[8]; uint4 q; } pk;
            pk.u[0] = f2bf(f0.x); pk.u[1] = f2bf(f0.y); pk.u[2] = f2bf(f0.z); pk.u[3] = f2bf(f0.w);
            pk.u[4] = f2bf(f1.x); pk.u[5] = f2bf(f1.y); pk.u[6] = f2bf(f1.z); pk.u[7] = f2bf(f1.w);
            A_stg[p * 64 + lane] = pk.q;
        }
        zs += __shfl_xor(zs, 16);        // combine lg quarters
        zs += __shfl_xor(zs, 32);
        if (lg == 0) zsqP[wid][l15] = zs;   // row (wid>>1)*16+l15, ks-half (wid&1)
    }

    // ---- chunk-0 B loads issued before the barrier (in flight during sync) ----
    const short8* bp = bfrag + (size_t)wid * 8192;   // wid*16 chunks * 8 ks * 64
    short8 bA[8], bB[8];
    #pragma unroll
    for (int ks = 0; ks < 8; ++ks) bA[ks] = bp[ks * 64 + lane];

    __syncthreads();   // A_stg / e_lds / zsqP / init visible

    if (tid < 32) {
        int rt = tid >> 4, r = tid & 15;
        zsq_s[tid] = zsqP[rt * 2][r] + zsqP[rt * 2 + 1][r];
    }

    // ---- fragment read-back: all 32 rows into registers (16 ds_read_b128) ----
    short8 a[2][8];
    #pragma unroll
    for (int rt = 0; rt < 2; ++rt)
        #pragma unroll
        for (int ks = 0; ks < 8; ++ks) {
            uint4 q = A_stg[(rt * 8 + ks) * 64 + lane];
            a[rt][ks] = *(short8*)&q;
        }

    float rm[2] = {1e30f, 1e30f};

    // ---- filter body for one 16-col chunk (swapped operands: C[col][row]) ----
    auto FILTER = [&](int ch, short8* b) {
        f32x4 acc[2];
        acc[0] = (f32x4){0.f, 0.f, 0.f, 0.f};
        acc[1] = (f32x4){0.f, 0.f, 0.f, 0.f};
        #pragma unroll
        for (int ks = 0; ks < 8; ++ks) {
            acc[0] = __builtin_amdgcn_mfma_f32_16x16x32_bf16(b[ks], a[0][ks], acc[0], 0, 0, 0);
            acc[1] = __builtin_amdgcn_mfma_f32_16x16x32_bf16(b[ks], a[1][ks], acc[1], 0, 0, 0);
        }
        const int cb = wid * 256 + ch * 16;
        const float4 eq = ((const float4*)e_lds)[(cb >> 2) + lg];  // cols cb+lg*4 ..+3
        #pragma unroll
        for (int rt = 0; rt < 2; ++rt) {
            float t0 = __fmaf_rn(-2.0f, acc[rt][0], eq.x);
            float t1 = __fmaf_rn(-2.0f, acc[rt][1], eq.y);
            float t2 = __fmaf_rn(-2.0f, acc[rt][2], eq.z);
            float t3 = __fmaf_rn(-2.0f, acc[rt][3], eq.w);
            float m = fminf(fminf(t0, t1), fminf(t2, t3));
            m = fminf(m, __shfl_xor(m, 16));   // combine the 4 lg col-groups
            m = fminf(m, __shfl_xor(m, 32));   // -> row-chunk min for row l15
            rm[rt] = fminf(rm[rt], m);
            const float thr = rm[rt] + MARGIN;
            const int rl = rt * 16 + l15;
            if (t0 <= thr) { int s = atomicAdd(&qcnt, 1); if (s < QCAP) queue[s] = make_uint2((rl << 10) | (cb + lg * 4 + 0), __float_as_uint(t0)); }
            if (t1 <= thr) { int s = atomicAdd(&qcnt, 1); if (s < QCAP) queue[s] = make_uint2((rl << 10) | (cb + lg * 4 + 1), __float_as_uint(t1)); }
            if (t2 <= thr) { int s = atomicAdd(&qcnt, 1); if (s < QCAP) queue[s] = make_uint2((rl << 10) | (cb + lg * 4 + 2), __float_as_uint(t2)); }
            if (t3 <= thr) { int s = atomicAdd(&qcnt, 1); if (s < QCAP) queue[s] = make_uint2((rl << 10) | (cb + lg * 4 + 3), __float_as_uint(t3)); }
        }
    };

    // ---- main loop: double-buffered B prefetch, barrier-free ----
    for (int ch = 0; ch < 16; ch += 2) {
        #pragma unroll
        for (int ks = 0; ks < 8; ++ks) bB[ks] = bp[((ch + 1) * 8 + ks) * 64 + lane];
        FILTER(ch, bA);
        if (ch + 2 < 16) {
            #pragma unroll
            for (int ks = 0; ks < 8; ++ks) bA[ks] = bp[((ch + 2) * 8 + ks) * 64 + lane];
        }
        FILTER(ch + 1, bB);
    }

    // ---- publish per-wave final mins; rmF = exact row min over 4 waves ----
    if (lg == 0) {
        rmW_s[wid][l15]      = rm[0];
        rmW_s[wid][16 + l15] = rm[1];
    }
    __syncthreads();
    if (tid < 32)
        rmF_s[tid] = fminf(fminf(rmW_s[0][tid], rmW_s[1][tid]),
                           fminf(rmW_s[2][tid], rmW_s[3][tid]));
    __syncthreads();

    // ---- cooperative exact refine: 8 lanes per candidate, post-filtered ----
    {
        int nq = qcnt; if (nq > QCAP) nq = QCAP;
        const int g = tid >> 3, q = tid & 7;      // 32 groups
        for (int e = g; e < nq; e += 32) {
            uint2 ent = queue[e];
            int rl = ent.x >> 10, col = ent.x & 1023;
            if (__uint_as_float(ent.y) > rmF_s[rl] + MARGIN) continue;  // cull
            const float4* zr = (const float4*)(z + (size_t)(row0 + rl) * EDIM);
            const float4* er = (const float4*)(emb + (size_t)col * EDIM);
            float ae = 0.f;
            #pragma unroll
            for (int i = 0; i < 8; ++i) {
                float4 x = zr[q + 8 * i], y = er[q + 8 * i];
                ae = __fmaf_rn(x.x, y.x, ae);
                ae = __fmaf_rn(x.y, y.y, ae);
                ae = __fmaf_rn(x.z, y.z, ae);
                ae = __fmaf_rn(x.w, y.w, ae);
            }
            ae = __fadd_rn(ae, __shfl_xor(ae, 1));
            ae = __fadd_rn(ae, __shfl_xor(ae, 2));
            ae = __fadd_rn(ae, __shfl_xor(ae, 4));
            if (q == 0) {
                float d = __fsub_rn(__fadd_rn(zsq_s[rl], e_lds[col]), __fmul_rn(2.0f, ae));
                unsigned u = __float_as_uint(d);
                u = (u & 0x80000000u) ? ~u : (u | 0x80000000u);   // order-preserving map
                unsigned long long key = ((unsigned long long)u << 32) | (unsigned)col;
                atomicMin(&best_s[rl], key);
            }
        }
    }

    __syncthreads();
    if (tid < 32) {
        unsigned long long k = best_s[tid];
        int id = (int)(k & 1023u);       // valid keys carry col in low bits;
                                         // clamp guards any unset row (no wild gather)
        idx_out[row0 + tid] = id;
        out_idx[row0 + tid] = (float)id;
        idx_s[tid] = id;
        atomicAdd(&cnt[id], 1);          // fused histogram
    }
    __syncthreads();

    // ---- z_q gather + store: one row per wave per iter (1KB contiguous) ----
    const float4* e4 = (const float4*)emb;
    #pragma unroll
    for (int i = 0; i < 8; ++i) {
        int flat = tid + i * 256;
        int r = flat >> 6, c4 = flat & 63;
        int id = idx_s[r];
        float4 e = e4[(size_t)id * 64 + c4];
        float* o = out_zq + (size_t)(row0 + r) * EDIM + c4 * 4;  // base odd-float: scalar stores
        o[0] = e.x; o[1] = e.y; o[2] = e.z; o[3] = e.w;
    }

    // ---- loss: decode the winning refined d per row (wave 0), accumulate ----
    if (wid == 0) {
        float lp = 0.f;
        if (lane < 32) {
            unsigned m = (unsigned)(best_s[lane] >> 32);
            unsigned bits = (m & 0x80000000u) ? (m & 0x7fffffffu) : ~m;
            lp = __uint_as_float(bits);
        }
        #pragma unroll
        for (int mm = 32; mm; mm >>= 1) lp += __shfl_down(lp, mm);
        if (lane == 0) atomicAdd(loss_acc, lp);
    }
}

// ---------------------------------------------------------------------------
// stats via counting sort: scan (offsets, N_t, counts) -> scatter -> msum
__global__ __launch_bounds__(1024) void scan_kernel(const int* __restrict__ cnt,
                                                    const float* __restrict__ N_t,
                                                    float* __restrict__ outN,
                                                    float* __restrict__ counts_f,
                                                    int* __restrict__ offs,
                                                    int* __restrict__ cursor) {
    __shared__ int s[1024];
    const int tid = threadIdx.x;
    int c = cnt[tid];
    s[tid] = c;
    __syncthreads();
    for (int d = 1; d < 1024; d <<= 1) {
        int v = (tid >= d) ? s[tid - d] : 0;
        __syncthreads();
        s[tid] += v;
        __syncthreads();
    }
    int excl = s[tid] - c;
    offs[tid] = excl;
    cursor[tid] = excl;
    counts_f[tid] = (float)c;
    float Nold = N_t[tid];
    outN[tid] = (c > 0) ? Nold * LAMBDA + (float)c * (1.0f - LAMBDA) : Nold;
}

__global__ __launch_bounds__(256) void scatter_kernel(const int* __restrict__ idx,
                                                      int* __restrict__ cursor,
                                                      int* __restrict__ sorted) {
    int i = blockIdx.x * 256 + threadIdx.x;
    int p = atomicAdd(&cursor[idx[i]], 1);
    sorted[p] = i;
}

__global__ __launch_bounds__(512) void msum_kernel(const float* __restrict__ z,
                                                   const int* __restrict__ sorted,
                                                   const int* __restrict__ offs,
                                                   const int* __restrict__ cnt,
                                                   const float* __restrict__ m_t,
                                                   float* __restrict__ outM) {
    const int j = blockIdx.x;
    const int tid = threadIdx.x, w = tid >> 6, lane = tid & 63;
    const int n = cnt[j], start = offs[j];
    float4 acc = make_float4(0.f, 0.f, 0.f, 0.f);
    for (int e = w; e < n; e += 8) {
        float4 v = ((const float4*)(z + (size_t)sorted[start + e] * EDIM))[lane];
        acc.x += v.x; acc.y += v.y; acc.z += v.z; acc.w += v.w;
    }
    __shared__ float red[8 * 256];
    *(float4*)(red + w * 256 + lane * 4) = acc;
    __syncthreads();
    if (tid < 256) {
        float s = 0.f;
        #pragma unroll
        for (int ww = 0; ww < 8; ++ww) s += red[ww * 256 + tid];
        float mold = m_t[(size_t)j * EDIM + tid];
        outM[(size_t)j * EDIM + tid] = (n > 0) ? mold * LAMBDA + s * (1.0f - LAMBDA) : mold;
    }
}

// ---------------------------------------------------------------------------
// finalize — UNCHANGED
__global__ __launch_bounds__(256) void final_kernel(const float* __restrict__ counts,
                                                    const float* __restrict__ loss_acc,
                                                    float* __restrict__ out_loss,
                                                    float* __restrict__ out_perp) {
    const int tid = threadIdx.x, w = tid >> 6, lane = tid & 63;
    float h = 0.f;
    for (int c = tid; c < NE; c += 256) {
        float em = counts[c] * (1.0f / (float)N_ROWS);
        h += em * logf(em + 1e-10f);
    }
    #pragma unroll
    for (int m = 32; m; m >>= 1) h += __shfl_down(h, m);
    __shared__ float red[4];
    if (lane == 0) red[w] = h;
    __syncthreads();
    if (tid == 0) {
        float H = red[0] + red[1] + red[2] + red[3];
        out_perp[0] = expf(-H);
        out_loss[0] = BETA * loss_acc[0] * (1.0f / (float)(N_ROWS * EDIM));
    }
}

// ---------------------------------------------------------------------------
extern "C" void kernel_launch(void* const* d_in, const int* in_sizes, int n_in,
                              void* d_out, int out_size, void* d_ws, size_t ws_size,
                              hipStream_t stream) {
    const float* z   = (const float*)d_in[0];
    const float* emb = (const float*)d_in[1];
    const float* N_t = (const float*)d_in[2];
    const float* m_t = (const float*)d_in[3];
    float* out = (float*)d_out;
    float* ws  = (float*)d_ws;

    float* loss_acc   = ws;
    float* e_sq       = ws + 64;
    unsigned* bfrag_u = (unsigned*)(ws + 67584);
    int*   sorted     = (int*)(ws + 198656);
    int*   idx1       = (int*)(ws + 264192);
    float* counts     = ws + 329728;
    int*   cnt_i      = (int*)(ws + 330752);
    int*   offs_i     = (int*)(ws + 331776);
    int*   cursor_i   = (int*)(ws + 332800);

    prep_b_kernel<<<NE, 64, 0, stream>>>(emb, bfrag_u, loss_acc, cnt_i);
    sq_kernel<<<NE / 16, 256, 0, stream>>>(emb, e_sq);
    argmin_kernel<<<N_ROWS / 32, 256, 0, stream>>>(z, emb, (const short8*)bfrag_u,
                                                   e_sq, idx1,
                                                   out + O_ZQ, out + O_IDX, loss_acc, cnt_i);
    scan_kernel<<<1, 1024, 0, stream>>>(cnt_i, N_t, out + O_NT, counts, offs_i, cursor_i);
    scatter_kernel<<<N_ROWS / 256, 256, 0, stream>>>(idx1, cursor_i, sorted);
    msum_kernel<<<NE, 512, 0, stream>>>(z, sorted, offs_i, cnt_i, m_t, out + O_MT);
    final_kernel<<<1, 256, 0, stream>>>(counts, loss_acc, out, out + O_PERP);
}